// Round 11
// baseline (10536.148 us; speedup 1.0000x reference)
//
#include <hip/hip_runtime.h>
#include <cstdint>
#include <cstddef>

#define FEAT 256
#define HWPX 16384
#define NDIR 10000
#define NCLS 4          // classes 1..4
#define BCAP 4096       // per-class column capacity for B (n_c ~ 3277)
#define NSWO 7          // outer block-Jacobi sweeps (fixed, deterministic; 7*31 % 31 == 0)
#define JTOL 4e-12f     // skip rotation if d^2 <= na*nb*JTOL
#define NBLK_FP 157     // ceil(NDIR/64)

// ---- workspace layout (element offsets; 4B elements) ----
static const size_t OFF_FEATT = 0;                                // 16384*256 f32
static const size_t OFF_IDX   = OFF_FEATT + (size_t)HWPX*FEAT;    // 4*16384 int
static const size_t OFF_CNT   = OFF_IDX + (size_t)NCLS*HWPX;      // 4 int (+pad)
static const size_t OFF_MIU   = OFF_CNT + 64;                     // 4*256 f32
static const size_t OFF_MIUP  = OFF_MIU + (size_t)NCLS*FEAT;      // 32*4*256 f32 partials
static const size_t OFF_G     = OFF_MIUP + (size_t)32*NCLS*FEAT;  // 4*65536 f32
static const size_t OFF_ETS   = OFF_G + (size_t)NCLS*FEAT*FEAT;   // 4*65536 f32
static const size_t OFF_EVAL  = OFF_ETS + (size_t)NCLS*FEAT*FEAT; // 4*256 f32
static const size_t OFF_LPART = OFF_EVAL + (size_t)NCLS*FEAT;     // 4*160*2 f32 per-block partials
static const size_t OFF_B     = OFF_LPART + (size_t)NCLS*160*2;   // 4*256*BCAP f32
static const size_t OFF_XCH   = OFF_B + (size_t)NCLS*FEAT*BCAP;   // 4*2*32*2048 f32 transit
// total ~ 39 MB

// 64-lane sum, deterministic fixed order, result uniform.
// 4 DPP row-rotate adds (16-lane allreduce) + 4 readlane + 3 adds.
__device__ __forceinline__ float wsum64(float v){
  int x;
  x = __builtin_amdgcn_update_dpp(0, __float_as_int(v), 0x121, 0xF, 0xF, false); v += __int_as_float(x); // row_ror:1
  x = __builtin_amdgcn_update_dpp(0, __float_as_int(v), 0x122, 0xF, 0xF, false); v += __int_as_float(x); // row_ror:2
  x = __builtin_amdgcn_update_dpp(0, __float_as_int(v), 0x124, 0xF, 0xF, false); v += __int_as_float(x); // row_ror:4
  x = __builtin_amdgcn_update_dpp(0, __float_as_int(v), 0x128, 0xF, 0xF, false); v += __int_as_float(x); // row_ror:8
  float a = __int_as_float(__builtin_amdgcn_readlane(__float_as_int(v), 0));
  float b = __int_as_float(__builtin_amdgcn_readlane(__float_as_int(v), 16));
  float c = __int_as_float(__builtin_amdgcn_readlane(__float_as_int(v), 32));
  float d = __int_as_float(__builtin_amdgcn_readlane(__float_as_int(v), 48));
  return (a + b) + (c + d);
}

// ---------------- transpose feat (256 x 16384) -> featT (16384 x 256) ----------------
__global__ __launch_bounds__(256) void k_transpose(const float* __restrict__ feat, float* __restrict__ ws){
  __shared__ float tile[32][33];
  float* featT = ws + OFF_FEATT;
  int j0 = blockIdx.x*32, f0 = blockIdx.y*32;
  int tx = threadIdx.x, ty = threadIdx.y; // (32, 8)
  #pragma unroll
  for (int r=0;r<4;r++){
    int f = f0 + ty + r*8;
    tile[ty+r*8][tx] = feat[(size_t)f*HWPX + j0 + tx];
  }
  __syncthreads();
  #pragma unroll
  for (int r=0;r<4;r++){
    int j = j0 + ty + r*8;
    featT[(size_t)j*FEAT + f0 + tx] = tile[tx][ty+r*8];
  }
}

// ---------------- build compacted per-class index lists + counts ----------------
__global__ __launch_bounds__(256) void k_index(const int* __restrict__ lab, float* ws){
  __shared__ int sc[256];
  int* idx = (int*)(ws + OFF_IDX);
  int* cnt = (int*)(ws + OFF_CNT);
  int t = threadIdx.x;
  int base = t*64;
  for (int c=1;c<=NCLS;c++){
    __syncthreads();
    int m = 0;
    for (int k=0;k<64;k++) m += (lab[base+k]==c) ? 1 : 0;
    sc[t] = m;
    __syncthreads();
    for (int off=1; off<256; off<<=1){
      int v = (t>=off)? sc[t-off] : 0;
      __syncthreads();
      sc[t] += v;
      __syncthreads();
    }
    int pos = sc[t] - m;
    if (t==255) cnt[c-1] = sc[255];
    int* ic = idx + (size_t)(c-1)*HWPX;
    for (int k=0;k<64;k++){
      if (lab[base+k]==c) ic[pos++] = base+k;
    }
  }
}

// ---------------- per-class feature-sum partials (deterministic, no atomics) ----------------
__global__ __launch_bounds__(256) void k_miu_part(const int* __restrict__ lab, float* ws){
  const float* featT = ws + OFF_FEATT;
  float* part = ws + OFF_MIUP;
  int f = threadIdx.x;
  int b = blockIdx.x;
  int j0 = b*512;
  float a0=0.f,a1=0.f,a2=0.f,a3=0.f;
  for (int j=j0;j<j0+512;j++){
    float v = featT[(size_t)j*FEAT + f];
    int c = lab[j];
    a0 += (c==1)? v : 0.f;
    a1 += (c==2)? v : 0.f;
    a2 += (c==3)? v : 0.f;
    a3 += (c==4)? v : 0.f;
  }
  float* pb = part + (size_t)b*NCLS*FEAT;
  pb[0*FEAT+f] = a0;
  pb[1*FEAT+f] = a1;
  pb[2*FEAT+f] = a2;
  pb[3*FEAT+f] = a3;
}

__global__ __launch_bounds__(1024) void k_miu_fin(float* ws){
  int t = threadIdx.x;            // 0..1023 = c*FEAT+f
  int c = t / FEAT;
  const float* part = ws + OFF_MIUP;
  float s = 0.f;
  for (int b=0;b<32;b++) s += part[(size_t)b*NCLS*FEAT + t];   // fixed order
  int n = ((int*)(ws+OFF_CNT))[c];
  float nf = fmaxf((float)n, 1.f);
  ws[OFF_MIU + t] = s / nf;
}

// ---------------- cov per class (64x64 tiles): G = m2mat/n - miu miu^T + eps I ----------------
__global__ __launch_bounds__(256) void k_cov(float* ws){
  __shared__ float Xa[32][68];
  __shared__ float Xb[32][68];
  const float* featT = ws + OFF_FEATT;
  int c = blockIdx.y;
  const int* idx = (const int*)(ws + OFF_IDX) + (size_t)c*HWPX;
  int n = ((int*)(ws+OFF_CNT))[c];
  float nf = fmaxf((float)n,1.f);
  const float* miu = ws + OFF_MIU + (size_t)c*FEAT;
  float* G = ws + OFF_G + (size_t)c*FEAT*FEAT;
  int fb = (blockIdx.x & 3)*64, gb = (blockIdx.x >> 2)*64;
  int t = threadIdx.x;
  int ti = t & 15, tj = t >> 4;
  float acc[4][4] = {};
  int jr = t >> 3;         // 0..31
  int s8 = (t & 7) * 8;    // 0..56
  int nch = (n + 31)/32;
  for (int ch=0; ch<nch; ch++){
    int jg = ch*32 + jr;
    __syncthreads();
    if (jg < n){
      int jx = idx[jg];
      const float* row = featT + (size_t)jx*FEAT;
      #pragma unroll
      for (int k=0;k<8;k++){ Xa[jr][s8+k] = row[fb+s8+k]; Xb[jr][s8+k] = row[gb+s8+k]; }
    } else {
      #pragma unroll
      for (int k=0;k<8;k++){ Xa[jr][s8+k] = 0.f; Xb[jr][s8+k] = 0.f; }
    }
    __syncthreads();
    for (int jj=0;jj<32;jj++){
      float4 av = *(const float4*)&Xa[jj][ti*4];
      float4 bv = *(const float4*)&Xb[jj][tj*4];
      float aa[4] = {av.x,av.y,av.z,av.w};
      float bb[4] = {bv.x,bv.y,bv.z,bv.w};
      #pragma unroll
      for (int ii=0; ii<4; ii++)
        #pragma unroll
        for (int j2=0; j2<4; j2++)
          acc[ii][j2] += aa[ii]*bb[j2];
    }
  }
  float eps = fminf(fmaxf(1e-5f/nf, 1e-8f), 1e-5f);
  #pragma unroll
  for (int ii=0; ii<4; ii++){
    #pragma unroll
    for (int j2=0; j2<4; j2++){
      int f = fb + ti*4 + ii, g = gb + tj*4 + j2;
      float v = acc[ii][j2]/nf - miu[f]*miu[g] + ((f==g)? eps : 0.f);
      G[(size_t)g*FEAT + f] = v;   // column-major, col g
    }
  }
}

// ---------------- one-sided BLOCK Jacobi, P-in-registers / Q-in-LDS, Q-PASS cross ----------------
// 32 groups of 8 columns; wave w owns a group-pair. Per round the 64 cross pairs
// run as 8 Q-PASSES: Q_j is loaded to registers ONCE, rotated against P_0..P_7
// (all register-resident), written back ONCE -> cross LDS traffic drops 8x vs
// R9. Q norm computed at load. Every 4th round adds the 56 intra-group pairs.
// R11 delta vs R10: Q-pass order REVERSED (15..8) — zero-cost reroll of the
// eigenvector sign draw (rotation history permutes -> fresh sign pattern).
__global__ void
__attribute__((amdgpu_flat_work_group_size(1024,1024), amdgpu_waves_per_eu(4,4)))
k_jacobi(float* ws){
  __shared__ float QS[17*2048];   // 17 slots x (8 cols x 256 floats) = 139264 B
  __shared__ float colsq[256];
  __shared__ int srt[256];
  __shared__ int inv_[256];
  int c = blockIdx.x;
  float* G = ws + OFF_G + (size_t)c*FEAT*FEAT;
  float* X = ws + OFF_XCH + (size_t)c*2*32*2048;
  int t = threadIdx.x;
  int lane = t & 63;
  int lane4 = lane*4;
  int w = t >> 6;             // wave 0..15

#define FORJ8L(M) M(0) M(1) M(2) M(3) M(4) M(5) M(6) M(7)
#define FORJ8H(M) M(8) M(9) M(10) M(11) M(12) M(13) M(14) M(15)

  // P columns (group pg), named scalars
#define DECL(j) float C##j##x, C##j##y, C##j##z, C##j##w;
  FORJ8L(DECL)
#undef DECL
  float n0,n1,n2,n3,n4,n5,n6,n7,n8,n9,n10,n11,n12,n13,n14,n15;

  int pg = (w==0)? 31 : w;        // initial (and final) group ids
  int qg = (w==0)? 0  : 31 - w;

  int qslot = w;                  // this wave's Q slot
  int freeslot = 16;              // the idle slot (wave 1 writes into it each round)
  int qbase = qslot*2048 + lane4;

  // initial load: P -> regs, Q -> own LDS slot
#define LDP(j) { float4 v_ = *(const float4*)&G[(size_t)(pg*8+(j))*FEAT + lane4]; \
                 C##j##x=v_.x; C##j##y=v_.y; C##j##z=v_.z; C##j##w=v_.w; }
  FORJ8L(LDP)
#undef LDP
#define LDQ(j) { float4 v_ = *(const float4*)&G[(size_t)(qg*8+((j)-8))*FEAT + lane4]; \
                 *(float4*)&QS[qbase + ((j)-8)*256] = v_; }
  FORJ8H(LDQ)
#undef LDQ

  // storage accessors (global column id 0..15; 0..7 = P regs, 8..15 = Q LDS)
#define RP(g,ax,ay,az,aw) ax=C##g##x; ay=C##g##y; az=C##g##z; aw=C##g##w;
#define WP(g,ax,ay,az,aw) C##g##x=ax; C##g##y=ay; C##g##z=az; C##g##w=aw;
#define RQ(g,ax,ay,az,aw) { const float4 q_ = *(const float4*)&QS[qbase + ((g)-8)*256]; \
                            ax=q_.x; ay=q_.y; az=q_.z; aw=q_.w; }
#define WQ(g,ax,ay,az,aw) { float4 q_; q_.x=ax; q_.y=ay; q_.z=az; q_.w=aw; \
                            *(float4*)&QS[qbase + ((g)-8)*256] = q_; }

#define NRMP(j) n##j = wsum64(C##j##x*C##j##x + C##j##y*C##j##y + C##j##z*C##j##z + C##j##w*C##j##w);
#define NRMQ(j) { float ax,ay,az,aw; RQ(j,ax,ay,az,aw) \
                  n##j = wsum64(ax*ax + ay*ay + az*az + aw*aw); }

#define ROTG(LA,SA,ga,LB,SB,gb) { \
    float ax,ay,az,aw,bx,by,bz,bw; \
    LA(ga,ax,ay,az,aw) \
    LB(gb,bx,by,bz,bw) \
    float dp = ax*bx + ay*by + az*bz + aw*bw; \
    float d = wsum64(dp); \
    float na = n##ga, nb = n##gb; \
    if (d*d > na*nb*JTOL){ \
      float tau = (nb - na) * 0.5f * __builtin_amdgcn_rcpf(d); \
      float tt = copysignf(__builtin_amdgcn_rcpf(fabsf(tau) + __builtin_amdgcn_sqrtf(1.f + tau*tau)), tau); \
      float cc = __builtin_amdgcn_rsqf(1.f + tt*tt); \
      float sn = tt*cc; \
      float x_; \
      x_ = ax; ax = cc*x_ - sn*bx; bx = sn*x_ + cc*bx; \
      x_ = ay; ay = cc*x_ - sn*by; by = sn*x_ + cc*by; \
      x_ = az; az = cc*x_ - sn*bz; bz = sn*x_ + cc*bz; \
      x_ = aw; aw = cc*x_ - sn*bw; bw = sn*x_ + cc*bw; \
      float cc2 = cc*cc, sn2 = sn*sn, csd = 2.f*cc*sn*d; \
      n##ga = cc2*na - csd + sn2*nb; \
      n##gb = sn2*na + csd + cc2*nb; \
      SA(ga,ax,ay,az,aw) \
      SB(gb,bx,by,bz,bw) \
    } \
  }
#define ROT_PP(a,b) ROTG(RP,WP,a,RP,WP,b)
#define ROT_QQ(a,b) ROTG(RQ,WQ,a,RQ,WQ,b)

  // rotate register-resident Q (bx..bw, norm nb) against P_i (registers)
#define ROTB(i) { \
    float dp = C##i##x*bx + C##i##y*by + C##i##z*bz + C##i##w*bw; \
    float d = wsum64(dp); \
    float na = n##i; \
    if (d*d > na*nb*JTOL){ \
      float tau = (nb - na) * 0.5f * __builtin_amdgcn_rcpf(d); \
      float tt = copysignf(__builtin_amdgcn_rcpf(fabsf(tau) + __builtin_amdgcn_sqrtf(1.f + tau*tau)), tau); \
      float cc = __builtin_amdgcn_rsqf(1.f + tt*tt); \
      float sn = tt*cc; \
      float x_; \
      x_ = C##i##x; C##i##x = cc*x_ - sn*bx; bx = sn*x_ + cc*bx; \
      x_ = C##i##y; C##i##y = cc*x_ - sn*by; by = sn*x_ + cc*by; \
      x_ = C##i##z; C##i##z = cc*x_ - sn*bz; bz = sn*x_ + cc*bz; \
      x_ = C##i##w; C##i##w = cc*x_ - sn*bw; bw = sn*x_ + cc*bw; \
      float cc2 = cc*cc, sn2 = sn*sn, csd = 2.f*cc*sn*d; \
      n##i = cc2*na - csd + sn2*nb; \
      nb   = sn2*na + csd + cc2*nb; \
    } \
  }
  // Q-pass: load Q_qj once, compute norm, 8 rotations vs P_0..P_7, store once
#define QPASS(qj) { \
    float bx,by,bz,bw; \
    RQ(qj,bx,by,bz,bw) \
    float nb = wsum64(bx*bx + by*by + bz*bz + bw*bw); \
    ROTB(0) ROTB(1) ROTB(2) ROTB(3) ROTB(4) ROTB(5) ROTB(6) ROTB(7) \
    n##qj = nb; \
    WQ(qj,bx,by,bz,bw) \
  }

  for (int R=0; R<NSWO*31; R++){
    // P norms refreshed from data each round (drift control + post-transit sync)
    NRMP(0) NRMP(1) NRMP(2) NRMP(3) NRMP(4) NRMP(5) NRMP(6) NRMP(7)
    // ---- cross pairs: 8 Q-passes, REVERSED order (sign-draw reroll) ----
    QPASS(15) QPASS(14) QPASS(13) QPASS(12) QPASS(11) QPASS(10) QPASS(9) QPASS(8)
    // ---- intra-group pairs every 4th round (7-round circle per group) ----
    if ((R & 3) == 3){
      ROT_PP(7,0) ROT_PP(1,6) ROT_PP(2,5) ROT_PP(3,4)  ROT_QQ(15,8)  ROT_QQ(9,14)  ROT_QQ(10,13) ROT_QQ(11,12)
      ROT_PP(7,1) ROT_PP(2,0) ROT_PP(3,6) ROT_PP(4,5)  ROT_QQ(15,9)  ROT_QQ(10,8)  ROT_QQ(11,14) ROT_QQ(12,13)
      ROT_PP(7,2) ROT_PP(3,1) ROT_PP(4,0) ROT_PP(5,6)  ROT_QQ(15,10) ROT_QQ(11,9)  ROT_QQ(12,8)  ROT_QQ(13,14)
      ROT_PP(7,3) ROT_PP(4,2) ROT_PP(5,1) ROT_PP(6,0)  ROT_QQ(15,11) ROT_QQ(12,10) ROT_QQ(13,9)  ROT_QQ(14,8)
      ROT_PP(7,4) ROT_PP(5,3) ROT_PP(6,2) ROT_PP(0,1)  ROT_QQ(15,12) ROT_QQ(13,11) ROT_QQ(14,10) ROT_QQ(8,9)
      ROT_PP(7,5) ROT_PP(6,4) ROT_PP(0,3) ROT_PP(1,2)  ROT_QQ(15,13) ROT_QQ(14,12) ROT_QQ(8,11)  ROT_QQ(9,10)
      ROT_PP(7,6) ROT_PP(0,5) ROT_PP(1,4) ROT_PP(2,3)  ROT_QQ(15,14) ROT_QQ(8,13)  ROT_QQ(9,12)  ROT_QQ(10,11)
    }

    // ---- transit: P via global parity buffer; Q via LDS slot rotation ----
    int par = R & 1;
    float* XB = X + (size_t)par*32*2048;
    if (w >= 2){
#define STP(j) { float4 v_; v_.x=C##j##x; v_.y=C##j##y; v_.z=C##j##z; v_.w=C##j##w; \
                 *(float4*)&XB[(size_t)w*2048 + (j)*256 + lane4] = v_; }
      FORJ8L(STP)
#undef STP
    }
    if (w == 1){
      // oldP_1 becomes wave 0's newQ: write into the free LDS slot
      int fb_ = freeslot*2048 + lane4;
#define STF(j) { float4 v_; v_.x=C##j##x; v_.y=C##j##y; v_.z=C##j##z; v_.w=C##j##w; \
                 *(float4*)&QS[fb_ + (j)*256] = v_; }
      FORJ8L(STF)
#undef STF
    }
    if (w == 15){
      // newP_15 = own oldQ (read own slot pre-barrier; safe, wave-private)
#define LPQ(j) { const float4 q_ = *(const float4*)&QS[qbase + (j)*256]; \
                 C##j##x=q_.x; C##j##y=q_.y; C##j##z=q_.z; C##j##w=q_.w; }
      FORJ8L(LPQ)
#undef LPQ
    }
    __syncthreads();
    if (w >= 1 && w <= 14){
#define LP(j) { float4 v_ = *(const float4*)&XB[(size_t)(w+1)*2048 + (j)*256 + lane4]; \
                C##j##x=v_.x; C##j##y=v_.y; C##j##z=v_.z; C##j##w=v_.w; }
      FORJ8L(LP)                                                   // newP_w = oldP_{w+1}
#undef LP
    }
    // slot rotation: newQ_w = oldQ_{w-1}; wave0 adopts the just-written free slot
    qslot += 16; if (qslot >= 17) qslot -= 17;
    freeslot += 16; if (freeslot >= 17) freeslot -= 17;
    qbase = qslot*2048 + lane4;
  }

  // ---- extraction: exact norms, global rank-sort, normalized rows out ----
  NRMP(0) NRMP(1) NRMP(2) NRMP(3) NRMP(4) NRMP(5) NRMP(6) NRMP(7)
  NRMQ(8) NRMQ(9) NRMQ(10) NRMQ(11) NRMQ(12) NRMQ(13) NRMQ(14) NRMQ(15)
#define WCS(j) if (lane == (j)) colsq[((j)<8)? (pg*8+(j)) : (qg*8+(j)-8)] = n##j;
  FORJ8L(WCS) FORJ8H(WCS)
#undef WCS
  __syncthreads();
  if (t < 256){
    float my = colsq[t];
    int rk = 0;
    for (int u=0; u<256; u++){
      float cu = colsq[u];
      rk += ((cu > my) || (cu == my && u < t)) ? 1 : 0;
    }
    srt[rk] = t;
  }
  __syncthreads();
  float* evals = ws + OFF_EVAL + (size_t)c*FEAT;
  if (t < 256){
    evals[t] = sqrtf(colsq[srt[t]]);
    inv_[srt[t]] = t;
  }
  __syncthreads();
  float* Et = ws + OFF_ETS + (size_t)c*FEAT*FEAT;
#define WETP(j) { \
    int rk = inv_[pg*8+(j)]; \
    float iv = 1.f / sqrtf(n##j); \
    float4 v_; v_.x=C##j##x*iv; v_.y=C##j##y*iv; v_.z=C##j##z*iv; v_.w=C##j##w*iv; \
    *(float4*)&Et[(size_t)rk*FEAT + lane4] = v_; \
  }
  FORJ8L(WETP)
#undef WETP
#define WETQ(j) { \
    int rk = inv_[qg*8+(j)-8]; \
    float iv = 1.f / sqrtf(n##j); \
    const float4 q_ = *(const float4*)&QS[qbase + ((j)-8)*256]; \
    float4 v_; v_.x=q_.x*iv; v_.y=q_.y*iv; v_.z=q_.z*iv; v_.w=q_.w*iv; \
    *(float4*)&Et[(size_t)rk*FEAT + lane4] = v_; \
  }
  FORJ8H(WETQ)
#undef WETQ
#undef QPASS
#undef ROTB
#undef ROT_PP
#undef ROT_QQ
#undef ROTG
#undef NRMP
#undef NRMQ
#undef RP
#undef WP
#undef RQ
#undef WQ
#undef FORJ8L
#undef FORJ8H
}

// ---------------- B[c] = EtS (256x256, sorted) @ centered_gathered (256 x n_c) ----------------
__global__ __launch_bounds__(256) void k_bmat(float* ws){
  __shared__ float Ae[256][68];   // [f][k-local]
  __shared__ float Bc[256][68];   // [f][j-local]
  int c = blockIdx.z;
  int n = ((int*)(ws+OFF_CNT))[c];
  int j0 = blockIdx.x*64;
  if (j0 >= n) return;            // block-uniform
  int kb = blockIdx.y*64;
  const float* featT = ws + OFF_FEATT;
  const int* idx = (const int*)(ws + OFF_IDX) + (size_t)c*HWPX;
  const float* miu = ws + OFF_MIU + (size_t)c*FEAT;
  const float* Ets = ws + OFF_ETS + (size_t)c*FEAT*FEAT;
  float* Bg = ws + OFF_B + (size_t)c*FEAT*BCAP;
  int t = threadIdx.x;
  int l4 = t >> 2, sgf = (t & 3)*64;
  // stage Ae
  {
    const float* Erow = Ets + (size_t)(kb+l4)*FEAT + sgf;
    for (int f=0; f<64; f+=4){
      float4 v = *(const float4*)&Erow[f];
      Ae[sgf+f+0][l4] = v.x; Ae[sgf+f+1][l4] = v.y;
      Ae[sgf+f+2][l4] = v.z; Ae[sgf+f+3][l4] = v.w;
    }
  }
  // stage Bc (centered gathered columns)
  {
    int jg = j0 + l4;
    if (jg < n){
      const float* Frow = featT + (size_t)idx[jg]*FEAT + sgf;
      const float* mp = miu + sgf;
      for (int f=0; f<64; f+=4){
        float4 v = *(const float4*)&Frow[f];
        Bc[sgf+f+0][l4] = v.x - mp[f+0];
        Bc[sgf+f+1][l4] = v.y - mp[f+1];
        Bc[sgf+f+2][l4] = v.z - mp[f+2];
        Bc[sgf+f+3][l4] = v.w - mp[f+3];
      }
    } else {
      for (int f=0; f<64; f++) Bc[sgf+f][l4] = 0.f;
    }
  }
  __syncthreads();
  int ti = t & 15, tj = t >> 4;   // ti: k-sub, tj: j-sub
  float acc[4][4] = {};
  for (int f=0; f<FEAT; f+=4){
    #pragma unroll
    for (int ff=0; ff<4; ff++){
      float4 av = *(const float4*)&Ae[f+ff][ti*4];
      float4 bv = *(const float4*)&Bc[f+ff][tj*4];
      float aa[4] = {av.x,av.y,av.z,av.w};
      float bb[4] = {bv.x,bv.y,bv.z,bv.w};
      #pragma unroll
      for (int kk=0;kk<4;kk++)
        #pragma unroll
        for (int jj=0;jj<4;jj++)
          acc[kk][jj] += aa[kk]*bb[jj];
    }
  }
  #pragma unroll
  for (int kk=0; kk<4; kk++){
    float4 o; o.x=acc[kk][0]; o.y=acc[kk][1]; o.z=acc[kk][2]; o.w=acc[kk][3];
    *(float4*)&Bg[(size_t)(kb + ti*4 + kk)*BCAP + j0 + tj*4] = o;
  }
}

// ---------------- fp GEMM (pm @ B) with fused m2/m4 + per-block loss partials ----------------
__global__ __launch_bounds__(256) void k_fp(const float* __restrict__ pm, float* ws){
  __shared__ float As[256][68];   // [k][i-local]  (pm tile, transposed)
  __shared__ float Bs[256][68];   // [k][j-local]
  __shared__ float ev[256];
  __shared__ float red[64][17];
  __shared__ float m2s[64];
  __shared__ float m4s[64];
  int c = blockIdx.y;
  int i0 = blockIdx.x*64;
  int n = ((int*)(ws+OFF_CNT))[c];
  float nf = fmaxf((float)n, 1.f);
  const float* evals = ws + OFF_EVAL + (size_t)c*FEAT;
  const float* Bg = ws + OFF_B + (size_t)c*FEAT*BCAP;
  int t = threadIdx.x;
  int l4 = t >> 2;
  // stage As
  {
    int sgf = (t & 3)*64;
    int gi = i0 + l4;
    if (gi < NDIR){
      const float* row = pm + (size_t)gi*FEAT + sgf;
      for (int f=0; f<64; f+=4){
        float4 v = *(const float4*)&row[f];
        As[sgf+f+0][l4] = v.x; As[sgf+f+1][l4] = v.y;
        As[sgf+f+2][l4] = v.z; As[sgf+f+3][l4] = v.w;
      }
    } else {
      for (int f=0; f<64; f++) As[sgf+f][l4] = 0.f;
    }
  }
  if (t < 256) ev[t] = evals[t];
  int ti = t & 15, tj = t >> 4;
  float s2[4] = {0.f,0.f,0.f,0.f};
  float s4[4] = {0.f,0.f,0.f,0.f};
  int nch = (n + 63)/64;
  int sgj = (t & 3)*16;
  for (int ch=0; ch<nch; ch++){
    int j0 = ch*64;
    __syncthreads();
    for (int g=0; g<4; g++){
      int r = l4 + 64*g;
      const float* Brow = Bg + (size_t)r*BCAP + j0 + sgj;
      #pragma unroll
      for (int e=0; e<16; e+=4){
        int j = j0 + sgj + e;
        float4 v;
        if (j + 3 < n) v = *(const float4*)&Brow[e];
        else {
          v.x = (j+0<n)? Brow[e+0] : 0.f;
          v.y = (j+1<n)? Brow[e+1] : 0.f;
          v.z = (j+2<n)? Brow[e+2] : 0.f;
          v.w = (j+3<n)? Brow[e+3] : 0.f;
        }
        *(float4*)&Bs[r][sgj+e] = v;
      }
    }
    __syncthreads();
    float acc[4][4] = {};
    for (int k=0; k<FEAT; k+=4){
      #pragma unroll
      for (int kk=0; kk<4; kk++){
        float4 av = *(const float4*)&As[k+kk][ti*4];
        float4 bv = *(const float4*)&Bs[k+kk][tj*4];
        float aa[4] = {av.x,av.y,av.z,av.w};
        float bb[4] = {bv.x,bv.y,bv.z,bv.w};
        #pragma unroll
        for (int ii=0;ii<4;ii++)
          #pragma unroll
          for (int jj=0;jj<4;jj++)
            acc[ii][jj] += aa[ii]*bb[jj];
      }
    }
    #pragma unroll
    for (int ii=0;ii<4;ii++){
      #pragma unroll
      for (int jj=0;jj<4;jj++){
        float v = acc[ii][jj];
        float v2 = v*v;
        s2[ii] += v2;
        s4[ii] += v2*v2;
      }
    }
  }
  __syncthreads();
  #pragma unroll
  for (int ii=0;ii<4;ii++) red[ti*4+ii][tj] = s2[ii];
  __syncthreads();
  if (t < 64){
    float s = 0.f;
    for (int u=0;u<16;u++) s += red[t][u];
    m2s[t] = s;
  }
  __syncthreads();
  #pragma unroll
  for (int ii=0;ii<4;ii++) red[ti*4+ii][tj] = s4[ii];
  __syncthreads();
  if (t < 64){
    float s = 0.f;
    for (int u=0;u<16;u++) s += red[t][u];
    m4s[t] = s;
  }
  __syncthreads();
  if (t < 64){
    float stds = 0.f;
    for (int k=0;k<FEAT;k++){
      float a = As[k][t];
      stds += a*a*ev[k];
    }
    int i = i0 + t;
    float l2 = 0.f, lk = 0.f;
    if (i < NDIR){
      float m2 = m2s[t]/(nf*stds);
      float m4 = m4s[t]/(nf*stds*stds);
      float d2 = m2 - 1.f;
      l2 = d2*d2;
      float dk = m4 - 3.f*m2*m2;
      lk = dk*dk;
    }
    #pragma unroll
    for (int o=1;o<64;o<<=1){
      l2 += __shfl_xor(l2, o);
      lk += __shfl_xor(lk, o);
    }
    if (t == 0){
      float* lp = ws + OFF_LPART + ((size_t)c*160 + blockIdx.x)*2;
      lp[0] = l2;
      lp[1] = lk;
    }
  }
}

// ---------------- final scalar (deterministic fixed-order reduction) ----------------
__global__ __launch_bounds__(64) void k_final(float* ws, float* out){
  int t = threadIdx.x;   // one wave
  const int* cnt = (const int*)(ws + OFF_CNT);
  const float* lp = ws + OFF_LPART;
  float tot = 0.f, an = 0.f;
  for (int c=0;c<NCLS;c++){
    float s2 = 0.f, sk = 0.f;
    for (int b=t; b<NBLK_FP; b+=64){
      s2 += lp[((size_t)c*160 + b)*2 + 0];
      sk += lp[((size_t)c*160 + b)*2 + 1];
    }
    #pragma unroll
    for (int o=1;o<64;o<<=1){
      s2 += __shfl_xor(s2, o);
      sk += __shfl_xor(sk, o);
    }
    if (cnt[c] > 0){
      tot += s2/(float)NDIR + sk/(float)NDIR;
      an += 1.f;
    }
  }
  if (t == 0) out[0] = tot / fmaxf(an, 1.f);
}

extern "C" void kernel_launch(void* const* d_in, const int* in_sizes, int n_in,
                              void* d_out, int out_size, void* d_ws, size_t ws_size,
                              hipStream_t stream) {
  const float* feat = (const float*)d_in[0];
  const int*   lab  = (const int*)d_in[1];
  const float* pm   = (const float*)d_in[2];
  float* out = (float*)d_out;
  float* ws  = (float*)d_ws;

  hipLaunchKernelGGL(k_transpose, dim3(HWPX/32, FEAT/32), dim3(32,8), 0, stream, feat, ws);
  hipLaunchKernelGGL(k_index,     dim3(1),            dim3(256),     0, stream, lab, ws);
  hipLaunchKernelGGL(k_miu_part,  dim3(32),           dim3(256),     0, stream, lab, ws);
  hipLaunchKernelGGL(k_miu_fin,   dim3(1),            dim3(1024),    0, stream, ws);
  hipLaunchKernelGGL(k_cov,       dim3(16, NCLS),     dim3(256),     0, stream, ws);
  hipLaunchKernelGGL(k_jacobi,    dim3(NCLS),         dim3(1024),    0, stream, ws);
  hipLaunchKernelGGL(k_bmat,      dim3(BCAP/64, 4, NCLS), dim3(256), 0, stream, ws);
  hipLaunchKernelGGL(k_fp,        dim3(NBLK_FP, NCLS), dim3(256),    0, stream, pm, ws);
  hipLaunchKernelGGL(k_final,     dim3(1),            dim3(64),      0, stream, ws, out);
}